// Round 5
// baseline (4616.765 us; speedup 1.0000x reference)
//
#include <hip/hip_runtime.h>

// ---------------- problem constants ----------------
constexpr int N_   = 512;
constexpr int PIX  = 1024;    // 32*32
constexpr int L_   = 1024;
constexpr int F_   = 32768;   // 32*32*32
constexpr int H_   = 512;
constexpr float IC_ = 1.0f / (float)(512 * 1024);   // 1/(N*PIX), BN count

__device__ __forceinline__ float lrelu(float t) { return t >= 0.f ? t : 0.01f * t; }

// ================= conv 3x3 SAME, NCHW — pipelined, fused BN + stats =========
// Software-pipelined: prefetch stage s+1 planes into registers during compute
// of stage s; double-buffered LDS tile; ONE barrier per stage. Removes the
// exposed global-load drain that held VALUBusy at 38% (rounds 2/4).
// Thread owns a 4-px vertical strip (rows y0..y0+3, col x) -> 2-way LDS reads
// (free). If BN_IN: BN+lrelu (raw sums in stats_in) applied in registers
// before LDS write. Epilogue: raw conv+bias store + per-channel sum/sumsq
// block-reduce into stats_out[{c, Cout+c}].
template<int CIN, int COPB, bool BN_IN>
__global__ __launch_bounds__(256, 4) void conv3x3(
    const float* __restrict__ in, const float* __restrict__ w,
    const float* __restrict__ bias, float* __restrict__ out,
    const float* __restrict__ stats_in, float* __restrict__ stats_out,
    int Cout)
{
    constexpr int CT     = (CIN < 4) ? CIN : 4;
    constexpr int NSTAGE = CIN / CT;
    __shared__ float tile[2 * CT * PIX];
    __shared__ float red[2 * COPB];
    const int groups = Cout / COPB;
    const int n   = blockIdx.x / groups;
    const int co0 = (blockIdx.x % groups) * COPB;
    const int tid = threadIdx.x;
    const int x   = tid & 31;
    const int y0  = (tid >> 5) * 4;

    float acc[COPB][4];
#pragma unroll
    for (int c = 0; c < COPB; ++c)
#pragma unroll
        for (int j = 0; j < 4; ++j) acc[c][j] = 0.f;

    const float* inbase = in + (size_t)n * CIN * PIX;

    auto bn4 = [&](float4 v, int c) -> float4 {
        if (BN_IN) {
            const float m   = stats_in[c] * IC_;
            const float q   = stats_in[CIN + c] * IC_;
            const float inv = rsqrtf(q - m * m + 1e-5f);
            v.x = lrelu((v.x - m) * inv);
            v.y = lrelu((v.y - m) * inv);
            v.z = lrelu((v.z - m) * inv);
            v.w = lrelu((v.w - m) * inv);
        }
        return v;
    };

    // ---- prologue: load + stage 0 ----
    float4 pf[CT];
#pragma unroll
    for (int s = 0; s < CT; ++s)
        pf[s] = ((const float4*)(inbase + (size_t)s * PIX))[tid];
#pragma unroll
    for (int s = 0; s < CT; ++s)
        ((float4*)tile)[s * 256 + tid] = bn4(pf[s], s);
    __syncthreads();

    int cur = 0;
#pragma unroll 1
    for (int st = 0; st < NSTAGE; ++st) {
        const bool more = (st + 1 < NSTAGE);
        // prefetch next stage (overlaps with compute below)
        if (more) {
#pragma unroll
            for (int s = 0; s < CT; ++s)
                pf[s] = ((const float4*)(inbase +
                         (size_t)((st + 1) * CT + s) * PIX))[tid];
        }
        // ---- compute stage st from tile[cur] ----
#pragma unroll 2
        for (int s = 0; s < CT; ++s) {
            const int ci = st * CT + s;
            const float* tp = tile + cur * (CT * PIX) + s * PIX;
            // window: rows y0-1..y0+4, cols x-1..x+1
            float r[6][3];
#pragma unroll
            for (int ry = 0; ry < 6; ++ry) {
                const int yy = y0 + ry - 1;
                const bool yok = (unsigned)yy < 32u;
#pragma unroll
                for (int cx = 0; cx < 3; ++cx) {
                    const int xx = x + cx - 1;
                    const bool ok = yok && ((unsigned)xx < 32u);
                    r[ry][cx] = ok ? tp[yy * 32 + xx] : 0.f;
                }
            }
#pragma unroll
            for (int c = 0; c < COPB; ++c) {
                const float* wp = w + ((size_t)(co0 + c) * CIN + ci) * 9;
#pragma unroll
                for (int ky = 0; ky < 3; ++ky)
#pragma unroll
                    for (int kx = 0; kx < 3; ++kx) {
                        const float wv = wp[ky * 3 + kx];
#pragma unroll
                        for (int j = 0; j < 4; ++j)
                            acc[c][j] += r[ky + j][kx] * wv;
                    }
            }
        }
        // ---- write prefetched stage st+1 to the other buffer ----
        if (more) {
            float* dst = tile + (cur ^ 1) * (CT * PIX);
#pragma unroll
            for (int s = 0; s < CT; ++s)
                ((float4*)dst)[s * 256 + tid] = bn4(pf[s], (st + 1) * CT + s);
        }
        __syncthreads();
        cur ^= 1;
    }

    // ---- epilogue: bias, store raw, per-channel stats ----
    if (tid < 2 * COPB) red[tid] = 0.f;
    __syncthreads();
#pragma unroll
    for (int c = 0; c < COPB; ++c) {
        const float b = bias[co0 + c];
        float* ob = out + (((size_t)n * Cout + co0 + c) << 10);
        float s = 0.f, q = 0.f;
#pragma unroll
        for (int j = 0; j < 4; ++j) {
            const float v = acc[c][j] + b;
            ob[(y0 + j) * 32 + x] = v;
            s += v; q += v * v;
        }
#pragma unroll
        for (int off = 32; off > 0; off >>= 1) {
            s += __shfl_down(s, off, 64);
            q += __shfl_down(q, off, 64);
        }
        if ((tid & 63) == 0) {
            atomicAdd(&red[c], s);
            atomicAdd(&red[COPB + c], q);
        }
    }
    __syncthreads();
    if (tid < COPB)
        atomicAdd(&stats_out[co0 + tid], red[tid]);
    else if (tid < 2 * COPB)
        atomicAdd(&stats_out[Cout + co0 + tid - COPB], red[tid]);
}

// ================= fp32 GEMM, 128x128 tile, 8x8 microtile, split-K atomics ===
// C[m][n] += sum_k A[m][k]*B[n][k]. Two heads fused via blockIdx.x.
// If BN_A: A is raw conv output, channel = k>>10, BN+lrelu while staging.
template<bool BN_A>
__global__ __launch_bounds__(256, 2) void gemm128(
    const float* __restrict__ A0, const float* __restrict__ A1,
    const float* __restrict__ B0, const float* __restrict__ B1,
    float* __restrict__ C0, float* __restrict__ C1,
    int K, int Nh, int kchunk, int xph,
    const float* __restrict__ bnstats, int Cin)
{
    __shared__ float As[16][132];
    __shared__ float Bs[16][132];
    const int tid  = threadIdx.x;
    const int head = blockIdx.x / xph;
    const int n0   = (blockIdx.x % xph) * 128;
    const int m0   = blockIdx.y * 128;
    const float* A = head ? A1 : A0;
    const float* B = head ? B1 : B0;
    float*       C = head ? C1 : C0;
    const int k0 = blockIdx.z * kchunk;
    const int k1 = k0 + kchunk;
    const int row = tid >> 2;          // 0..63
    const int kq  = (tid & 3) * 4;     // 0,4,8,12
    const int tx  = tid & 15, ty = tid >> 4;

    float acc[8][8];
#pragma unroll
    for (int i = 0; i < 8; ++i)
#pragma unroll
        for (int j = 0; j < 8; ++j) acc[i][j] = 0.f;

    for (int kb = k0; kb < k1; kb += 16) {
        __syncthreads();
#pragma unroll
        for (int s = 0; s < 2; ++s) {
            const int r = row + s * 64;
            float4 av = *(const float4*)(A + (size_t)(m0 + r) * K + kb + kq);
            if (BN_A) {
                const int c = (kb + kq) >> 10;
                const float m   = bnstats[c] * IC_;
                const float q   = bnstats[Cin + c] * IC_;
                const float inv = rsqrtf(q - m * m + 1e-5f);
                av.x = lrelu((av.x - m) * inv);
                av.y = lrelu((av.y - m) * inv);
                av.z = lrelu((av.z - m) * inv);
                av.w = lrelu((av.w - m) * inv);
            }
            As[kq + 0][r] = av.x; As[kq + 1][r] = av.y;
            As[kq + 2][r] = av.z; As[kq + 3][r] = av.w;
            float4 bv = *(const float4*)(B + (size_t)(n0 + r) * K + kb + kq);
            Bs[kq + 0][r] = bv.x; Bs[kq + 1][r] = bv.y;
            Bs[kq + 2][r] = bv.z; Bs[kq + 3][r] = bv.w;
        }
        __syncthreads();
#pragma unroll
        for (int kk = 0; kk < 16; ++kk) {
            const float4 a0 = *(const float4*)&As[kk][ty * 4];
            const float4 a1 = *(const float4*)&As[kk][64 + ty * 4];
            const float4 b0 = *(const float4*)&Bs[kk][tx * 4];
            const float4 b1 = *(const float4*)&Bs[kk][64 + tx * 4];
            const float ar[8] = {a0.x, a0.y, a0.z, a0.w, a1.x, a1.y, a1.z, a1.w};
            const float br[8] = {b0.x, b0.y, b0.z, b0.w, b1.x, b1.y, b1.z, b1.w};
#pragma unroll
            for (int i = 0; i < 8; ++i)
#pragma unroll
                for (int j = 0; j < 8; ++j)
                    acc[i][j] += ar[i] * br[j];
        }
    }
#pragma unroll
    for (int i = 0; i < 8; ++i) {
        const int m = m0 + ((i >> 2) << 6) + ty * 4 + (i & 3);
        float* crow = C + (size_t)m * Nh + n0;
#pragma unroll
        for (int j = 0; j < 8; ++j) {
            const int nn = ((j >> 2) << 6) + tx * 4 + (j & 3);
            atomicAdd(&crow[nn], acc[i][j]);
        }
    }
}

// ================= bias + leaky relu, in place =================
__global__ __launch_bounds__(256) void bias_lrelu_kernel(
    float* __restrict__ buf, const float* __restrict__ b, int Nn, int total)
{
    const int idx = blockIdx.x * 256 + threadIdx.x;
    if (idx >= total) return;
    buf[idx] = lrelu(buf[idx] + b[idx % Nn]);
}

// ================= block reduce + atomic helper =================
__device__ __forceinline__ void block_reduce_atomic(float t, float* target)
{
#pragma unroll
    for (int off = 32; off > 0; off >>= 1) t += __shfl_down(t, off, 64);
    __shared__ float lt[4];
    const int wave = threadIdx.x >> 6, lane = threadIdx.x & 63;
    if (lane == 0) lt[wave] = t;
    __syncthreads();
    if (threadIdx.x == 0) atomicAdd(target, lt[0] + lt[1] + lt[2] + lt[3]);
}

// ================= product-of-experts group posterior + kl2 =================
__global__ __launch_bounds__(256) void poe_kernel(
    const float* __restrict__ mu1, const float* __restrict__ lv1,
    float* __restrict__ gmu, float* __restrict__ glv, float* __restrict__ kl)
{
    const int l = blockIdx.x * 256 + threadIdx.x;   // 0..1023 (exact)
    float sp = 0.f, sm = 0.f;
    for (int n = 0; n < N_; ++n) {
        const float lv = lv1[(size_t)n * L_ + l];
        const float p  = expf(-lv);
        sp += p;
        sm += mu1[(size_t)n * L_ + l] * p;
    }
    const float gv = 1.f / sp;
    const float gm = sm * gv;
    const float gl = -logf(sp);
    gmu[l] = gm;
    glv[l] = gl;
    const float t = -0.5f * (1.f + gl) + 0.5f * (gm * gm + gv * gv);
    block_reduce_atomic(t, &kl[1]);
}

// ================= reparameterize + kl1 =================
__global__ __launch_bounds__(256) void reparam_kernel(
    const float* __restrict__ mu0, const float* __restrict__ lv0,
    const float* __restrict__ eps_c, const float* __restrict__ eps_s,
    const float* __restrict__ gmu, const float* __restrict__ glv,
    float* __restrict__ zc, float* __restrict__ zs, float* __restrict__ kl)
{
    const int idx = blockIdx.x * 256 + threadIdx.x;   // 0..524287 (exact)
    const int l = idx & (L_ - 1);
    const float m  = mu0[idx];
    const float lv = lv0[idx];
    zc[idx] = eps_c[idx] * expf(0.5f * lv) + m;
    zs[idx] = eps_s[idx] * expf(0.5f * glv[l]) + gmu[l];
    const float e = expf(lv);
    const float t = -0.5f * (1.f + lv) + 0.5f * (m * m + e * e);
    block_reduce_atomic(t, &kl[0]);
}

// ================= final: BN of decoder outputs + output + loss ============
__global__ __launch_bounds__(256) void final_kernel(
    const float* __restrict__ x, const float* __restrict__ oc,
    const float* __restrict__ os, const float* __restrict__ stC,
    const float* __restrict__ stS, const float* __restrict__ kl,
    float* __restrict__ out)
{
    const int idx = blockIdx.x * 256 + threadIdx.x;   // 0..524287 (exact)
    const float mc = stC[0] * IC_, qc = stC[1] * IC_;
    const float ivc = rsqrtf(qc - mc * mc + 1e-5f);
    const float ms = stS[0] * IC_, qs = stS[1] * IC_;
    const float ivs = rsqrtf(qs - ms * ms + 1e-5f);
    const float tc = lrelu((oc[idx] - mc) * ivc);          // output_c (bn+lrelu)
    const float ts = fmaxf((os[idx] - ms) * ivs, 0.f);     // relu(lrelu(bn)) = relu(bn)
    const float o = tc * ts;
    const float d = expf(x[idx]) - expf(o);
    out[idx]            = -kl[0] + kl[1] + d * d;
    out[N_ * PIX + idx] = o;
}

// ================= host launch =================
extern "C" void kernel_launch(void* const* d_in, const int* in_sizes, int n_in,
                              void* d_out, int out_size, void* d_ws, size_t ws_size,
                              hipStream_t stream)
{
    const float* x        = (const float*)d_in[0];
    const float* eps_c    = (const float*)d_in[1];
    const float* eps_s    = (const float*)d_in[2];
    const float* enc_cw1  = (const float*)d_in[3];
    const float* enc_cb1  = (const float*)d_in[4];
    const float* enc_cw2  = (const float*)d_in[5];
    const float* enc_cb2  = (const float*)d_in[6];
    const float* enc_cw3  = (const float*)d_in[7];
    const float* enc_cb3  = (const float*)d_in[8];
    const float* enc_muW1 = (const float*)d_in[9];
    const float* enc_muB1 = (const float*)d_in[10];
    const float* enc_muW2 = (const float*)d_in[11];
    const float* enc_muB2 = (const float*)d_in[12];
    const float* enc_vaW1 = (const float*)d_in[13];
    const float* enc_vaB1 = (const float*)d_in[14];
    const float* enc_vaW2 = (const float*)d_in[15];
    const float* enc_vaB2 = (const float*)d_in[16];
    const float* dec_cw1  = (const float*)d_in[17];
    const float* dec_cb1  = (const float*)d_in[18];
    const float* dec_cw2  = (const float*)d_in[19];
    const float* dec_cb2  = (const float*)d_in[20];
    const float* dec_cw3  = (const float*)d_in[21];
    const float* dec_cb3  = (const float*)d_in[22];
    float* out = (float*)d_out;

    // ---- workspace layout (floats) ----
    float* ws   = (float*)d_ws;
    float* bufA = ws;                             // N*64*PIX
    float* bufB = bufA + (size_t)N_ * 64 * PIX;   // N*32*PIX
    float* h1   = bufB + (size_t)N_ * 32 * PIX;   // N*H
    float* h2   = h1 + N_ * H_;
    float* mu0  = h2 + N_ * H_;                   // N*L each below
    float* lv0  = mu0 + N_ * L_;
    float* mu1  = lv0 + N_ * L_;
    float* lv1  = mu1 + N_ * L_;
    float* zc   = lv1 + N_ * L_;
    float* zs   = zc + N_ * L_;
    float* oc   = zs + N_ * L_;
    float* os   = oc + N_ * L_;
    float* gmu  = os + N_ * L_;                   // L
    float* glv  = gmu + L_;                       // L
    float* stats = glv + L_;                      // 12 slots x 128
    float* kl   = stats + 12 * 128;               // 2

    auto st = [&](int s) { return stats + 128 * s; };

    hipMemsetAsync(stats, 0, 12 * 128 * sizeof(float), stream);
    hipMemsetAsync(kl, 0, 2 * sizeof(float), stream);

    // ================== encoders ==================
    for (int i = 0; i < 2; ++i) {
        const float* cw1 = enc_cw1 + (size_t)i * 32 * 9;
        const float* cb1 = enc_cb1 + (size_t)i * 32;
        const float* cw2 = enc_cw2 + (size_t)i * 64 * 32 * 9;
        const float* cb2 = enc_cb2 + (size_t)i * 64;
        const float* cw3 = enc_cw3 + (size_t)i * 32 * 64 * 9;
        const float* cb3 = enc_cb3 + (size_t)i * 32;

        conv3x3<1, 16, false><<<N_ * 2, 256, 0, stream>>>(
            x, cw1, cb1, bufB, nullptr, st(i * 3 + 0), 32);
        conv3x3<32, 16, true><<<N_ * 4, 256, 0, stream>>>(
            bufB, cw2, cb2, bufA, st(i * 3 + 0), st(i * 3 + 1), 64);
        conv3x3<64, 16, true><<<N_ * 2, 256, 0, stream>>>(
            bufA, cw3, cb3, bufB, st(i * 3 + 1), st(i * 3 + 2), 32);
        // bufB = raw conv3 out; BN+lrelu fused into GEMM A staging

        const float* W1m = enc_muW1 + (size_t)i * H_ * F_;
        const float* B1m = enc_muB1 + (size_t)i * H_;
        const float* W2m = enc_muW2 + (size_t)i * L_ * H_;
        const float* B2m = enc_muB2 + (size_t)i * L_;
        const float* W1v = enc_vaW1 + (size_t)i * H_ * F_;
        const float* B1v = enc_vaB1 + (size_t)i * H_;
        const float* W2v = enc_vaW2 + (size_t)i * L_ * H_;
        const float* B2v = enc_vaB2 + (size_t)i * L_;
        float* mu_i = (i == 0) ? mu0 : mu1;
        float* lv_i = (i == 0) ? lv0 : lv1;

        hipMemsetAsync(h1, 0, (size_t)N_ * H_ * sizeof(float), stream);
        hipMemsetAsync(h2, 0, (size_t)N_ * H_ * sizeof(float), stream);
        // fused mu+va heads: grid.x = 2 heads * (512/128) = 8
        gemm128<true><<<dim3(8, 4, 16), 256, 0, stream>>>(
            bufB, bufB, W1m, W1v, h1, h2, F_, H_, 2048, 4, st(i * 3 + 2), 32);
        bias_lrelu_kernel<<<(N_ * H_) / 256, 256, 0, stream>>>(h1, B1m, H_, N_ * H_);
        bias_lrelu_kernel<<<(N_ * H_) / 256, 256, 0, stream>>>(h2, B1v, H_, N_ * H_);

        hipMemsetAsync(mu_i, 0, (size_t)N_ * L_ * sizeof(float), stream);
        hipMemsetAsync(lv_i, 0, (size_t)N_ * L_ * sizeof(float), stream);
        gemm128<false><<<dim3(16, 4, 4), 256, 0, stream>>>(
            h1, h2, W2m, W2v, mu_i, lv_i, H_, L_, 128, 8, nullptr, 0);
        bias_lrelu_kernel<<<(N_ * L_) / 256, 256, 0, stream>>>(mu_i, B2m, L_, N_ * L_);
        bias_lrelu_kernel<<<(N_ * L_) / 256, 256, 0, stream>>>(lv_i, B2v, L_, N_ * L_);
    }

    // ================== PoE + reparam + KL ==================
    poe_kernel<<<L_ / 256, 256, 0, stream>>>(mu1, lv1, gmu, glv, kl);
    reparam_kernel<<<(N_ * L_) / 256, 256, 0, stream>>>(
        mu0, lv0, eps_c, eps_s, gmu, glv, zc, zs, kl);

    // ================== decoders ==================
    for (int i = 0; i < 2; ++i) {
        const float* cw1 = dec_cw1 + (size_t)i * 32 * 9;
        const float* cb1 = dec_cb1 + (size_t)i * 32;
        const float* cw2 = dec_cw2 + (size_t)i * 64 * 32 * 9;
        const float* cb2 = dec_cb2 + (size_t)i * 64;
        const float* cw3 = dec_cw3 + (size_t)i * 64 * 9;
        const float* cb3 = dec_cb3 + (size_t)i * 1;
        const float* zi = (i == 0) ? zc : zs;
        float* oi = (i == 0) ? oc : os;

        conv3x3<1, 16, false><<<N_ * 2, 256, 0, stream>>>(
            zi, cw1, cb1, bufB, nullptr, st(6 + i * 3 + 0), 32);
        conv3x3<32, 16, true><<<N_ * 4, 256, 0, stream>>>(
            bufB, cw2, cb2, bufA, st(6 + i * 3 + 0), st(6 + i * 3 + 1), 64);
        conv3x3<64, 1, true><<<N_, 256, 0, stream>>>(
            bufA, cw3, cb3, oi, st(6 + i * 3 + 1), st(6 + i * 3 + 2), 1);
    }

    // ================== output + loss (BN of oc/os fused) ==================
    final_kernel<<<(N_ * PIX) / 256, 256, 0, stream>>>(
        x, oc, os, st(8), st(11), kl, out);
}

// Round 6
// 3575.993 us; speedup vs baseline: 1.2910x; 1.2910x over previous
//
#include <hip/hip_runtime.h>

// ---------------- problem constants ----------------
constexpr int N_   = 512;
constexpr int PIX  = 1024;    // 32*32
constexpr int L_   = 1024;
constexpr int F_   = 32768;   // 32*32*32
constexpr int H_   = 512;
constexpr float IC_ = 1.0f / (float)(512 * 1024);   // 1/(N*PIX), BN count

__device__ __forceinline__ float lrelu(float t) { return t >= 0.f ? t : 0.01f * t; }

using frag  = __attribute__((ext_vector_type(8))) short;   // 8 bf16 (4 VGPRs)
using f32x4 = __attribute__((ext_vector_type(4))) float;   // MFMA accum

// split v = hi + lo, both bf16 (truncation; lo captures the tail exactly,
// dropped lo*lo term ~2^-16 relative)
__device__ __forceinline__ void split_bf16(float v, short& hi, short& lo) {
    const unsigned b = __float_as_uint(v);
    hi = (short)(b >> 16);
    const float hf = __uint_as_float(b & 0xFFFF0000u);
    lo = (short)(__float_as_uint(v - hf) >> 16);
}

// ================= conv 3x3 SAME, NCHW — round-4 proven version ==============
// (VGPR=84, 608 us for conv2-class; do NOT add waves/EU floors or halo pads —
// rounds 3/5 showed both regress via VGPR pressure / spills.)
template<int CIN, int COPB, bool BN_IN>
__global__ __launch_bounds__(256) void conv3x3(
    const float* __restrict__ in, const float* __restrict__ w,
    const float* __restrict__ bias, float* __restrict__ out,
    const float* __restrict__ stats_in, float* __restrict__ stats_out,
    int Cout)
{
    constexpr int CT = (CIN < 4) ? CIN : 4;
    __shared__ float tile[CT * PIX];
    __shared__ float red[2 * COPB];
    const int groups = Cout / COPB;
    const int n   = blockIdx.x / groups;
    const int co0 = (blockIdx.x % groups) * COPB;
    const int tid = threadIdx.x;
    const int x   = tid & 31;
    const int y0  = (tid >> 5) * 4;

    float acc[COPB][4];
#pragma unroll
    for (int c = 0; c < COPB; ++c)
#pragma unroll
        for (int j = 0; j < 4; ++j) acc[c][j] = 0.f;

    const float* inbase = in + (size_t)n * CIN * PIX;

#pragma unroll 1
    for (int s0 = 0; s0 < CIN; s0 += CT) {
        __syncthreads();
#pragma unroll
        for (int s = 0; s < CT; ++s) {
            float4 v = ((const float4*)(inbase + (size_t)(s0 + s) * PIX))[tid];
            if (BN_IN) {
                const int c = s0 + s;
                const float m   = stats_in[c] * IC_;
                const float q   = stats_in[CIN + c] * IC_;
                const float inv = rsqrtf(q - m * m + 1e-5f);
                v.x = lrelu((v.x - m) * inv);
                v.y = lrelu((v.y - m) * inv);
                v.z = lrelu((v.z - m) * inv);
                v.w = lrelu((v.w - m) * inv);
            }
            ((float4*)tile)[s * 256 + tid] = v;
        }
        __syncthreads();
#pragma unroll 2
        for (int s = 0; s < CT; ++s) {
            const int ci = s0 + s;
            const float* tp = tile + s * PIX;
            float r[6][3];
#pragma unroll
            for (int ry = 0; ry < 6; ++ry) {
                const int yy = y0 + ry - 1;
                const bool yok = (unsigned)yy < 32u;
#pragma unroll
                for (int cx = 0; cx < 3; ++cx) {
                    const int xx = x + cx - 1;
                    const bool ok = yok && ((unsigned)xx < 32u);
                    r[ry][cx] = ok ? tp[yy * 32 + xx] : 0.f;
                }
            }
#pragma unroll
            for (int c = 0; c < COPB; ++c) {
                const float* wp = w + ((size_t)(co0 + c) * CIN + ci) * 9;
#pragma unroll
                for (int ky = 0; ky < 3; ++ky)
#pragma unroll
                    for (int kx = 0; kx < 3; ++kx) {
                        const float wv = wp[ky * 3 + kx];
#pragma unroll
                        for (int j = 0; j < 4; ++j)
                            acc[c][j] += r[ky + j][kx] * wv;
                    }
            }
        }
    }

    if (tid < 2 * COPB) red[tid] = 0.f;
    __syncthreads();
#pragma unroll
    for (int c = 0; c < COPB; ++c) {
        const float b = bias[co0 + c];
        float* ob = out + (((size_t)n * Cout + co0 + c) << 10);
        float s = 0.f, q = 0.f;
#pragma unroll
        for (int j = 0; j < 4; ++j) {
            const float v = acc[c][j] + b;
            ob[(y0 + j) * 32 + x] = v;
            s += v; q += v * v;
        }
#pragma unroll
        for (int off = 32; off > 0; off >>= 1) {
            s += __shfl_down(s, off, 64);
            q += __shfl_down(q, off, 64);
        }
        if ((tid & 63) == 0) {
            atomicAdd(&red[c], s);
            atomicAdd(&red[COPB + c], q);
        }
    }
    __syncthreads();
    if (tid < COPB)
        atomicAdd(&stats_out[co0 + tid], red[tid]);
    else if (tid < 2 * COPB)
        atomicAdd(&stats_out[Cout + co0 + tid - COPB], red[tid]);
}

// ======== split-bf16 MFMA GEMM: C[m][n] += sum_k A[m][k]*B[n][k] ============
// 3-pass split precision: A=ah+al, B=bh+bl; D += ah*bh + ah*bl + al*bh.
// Block 256 = 4 waves; tile 128(m) x 128(n); BK=32 fp32 k per iter.
// LDS holds hi/lo fragments in FRAGMENT ORDER: frag(mt,q,lm) contiguous 16B,
// so a wave's ds_read_b128 covers a contiguous 1KB span (conflict-free).
// Two heads fused via blockIdx.x; split-K via blockIdx.z + atomic epilogue.
// If BN_A: A is raw conv output (channel = k>>10), BN+lrelu in staging.
template<bool BN_A>
__global__ __launch_bounds__(256) void gemm_mfma(
    const float* __restrict__ A0, const float* __restrict__ A1,
    const float* __restrict__ B0, const float* __restrict__ B1,
    float* __restrict__ C0, float* __restrict__ C1,
    int K, int Nh, int kchunk, int xph,
    const float* __restrict__ bnstats, int Cin)
{
    __shared__ short AhL[4096], AlL[4096], BhL[4096], BlL[4096];  // 32 KB
    const int tid  = threadIdx.x;
    const int head = blockIdx.x / xph;
    const int n0   = (blockIdx.x % xph) * 128;
    const int m0   = blockIdx.y * 128;
    const float* A = head ? A1 : A0;
    const float* B = head ? B1 : B0;
    float*       C = head ? C1 : C0;
    const int k0 = blockIdx.z * kchunk;
    const int k1 = k0 + kchunk;

    const int lane = tid & 63;
    const int wv   = tid >> 6;
    const int wm   = wv & 1;          // wave's 64-row half
    const int wn   = wv >> 1;         // wave's 64-col half
    const int lm   = lane & 15;
    const int q    = lane >> 4;

    // staging coords: thread covers (row, 16-k segment)
    const int srow = tid >> 1;        // 0..127
    const int smt  = srow >> 4;
    const int slm  = srow & 15;
    const int sq0  = (tid & 1) * 2;   // first of two 8-k quads
    const int ks   = (tid & 1) * 16;  // k offset within BK

    f32x4 acc[4][4];
#pragma unroll
    for (int i = 0; i < 4; ++i)
#pragma unroll
        for (int j = 0; j < 4; ++j) acc[i][j] = {0.f, 0.f, 0.f, 0.f};

    auto cv8 = [](float4 u, float4 w2, frag& h, frag& l) {
        const float v[8] = {u.x, u.y, u.z, u.w, w2.x, w2.y, w2.z, w2.w};
#pragma unroll
        for (int e = 0; e < 8; ++e) {
            short hh, ll;
            split_bf16(v[e], hh, ll);
            h[e] = hh; l[e] = ll;
        }
    };

#pragma unroll 1
    for (int kb = k0; kb < k1; kb += 32) {
        const float* Ap = A + (size_t)(m0 + srow) * K + kb + ks;
        const float* Bp = B + (size_t)(n0 + srow) * K + kb + ks;
        float4 a4[4], b4[4];
#pragma unroll
        for (int g = 0; g < 4; ++g) a4[g] = ((const float4*)Ap)[g];
#pragma unroll
        for (int g = 0; g < 4; ++g) b4[g] = ((const float4*)Bp)[g];

        if (BN_A) {   // 16-k segment never crosses a 1024-px channel
            const int c = (kb + ks) >> 10;
            const float m   = bnstats[c] * IC_;
            const float qq  = bnstats[Cin + c] * IC_;
            const float inv = rsqrtf(qq - m * m + 1e-5f);
#pragma unroll
            for (int g = 0; g < 4; ++g) {
                a4[g].x = lrelu((a4[g].x - m) * inv);
                a4[g].y = lrelu((a4[g].y - m) * inv);
                a4[g].z = lrelu((a4[g].z - m) * inv);
                a4[g].w = lrelu((a4[g].w - m) * inv);
            }
        }

        frag ah0, al0, ah1, al1, bh0, bl0, bh1, bl1;
        cv8(a4[0], a4[1], ah0, al0);
        cv8(a4[2], a4[3], ah1, al1);
        cv8(b4[0], b4[1], bh0, bl0);
        cv8(b4[2], b4[3], bh1, bl1);

        __syncthreads();   // previous iter's compute done
        const int o0 = ((smt * 4 + sq0) * 16 + slm) * 8;
        const int o1 = ((smt * 4 + sq0 + 1) * 16 + slm) * 8;
        *(frag*)&AhL[o0] = ah0;  *(frag*)&AhL[o1] = ah1;
        *(frag*)&AlL[o0] = al0;  *(frag*)&AlL[o1] = al1;
        *(frag*)&BhL[o0] = bh0;  *(frag*)&BhL[o1] = bh1;
        *(frag*)&BlL[o0] = bl0;  *(frag*)&BlL[o1] = bl1;
        __syncthreads();

        frag fah[4], fal[4], fbh[4], fbl[4];
#pragma unroll
        for (int t = 0; t < 4; ++t) {
            const int oa = (((wm * 4 + t) * 4 + q) * 16 + lm) * 8;
            const int ob = (((wn * 4 + t) * 4 + q) * 16 + lm) * 8;
            fah[t] = *(const frag*)&AhL[oa];
            fal[t] = *(const frag*)&AlL[oa];
            fbh[t] = *(const frag*)&BhL[ob];
            fbl[t] = *(const frag*)&BlL[ob];
        }
#pragma unroll
        for (int i = 0; i < 4; ++i)
#pragma unroll
            for (int j = 0; j < 4; ++j) {
                acc[i][j] = __builtin_amdgcn_mfma_f32_16x16x32_bf16(
                    fah[i], fbh[j], acc[i][j], 0, 0, 0);
                acc[i][j] = __builtin_amdgcn_mfma_f32_16x16x32_bf16(
                    fah[i], fbl[j], acc[i][j], 0, 0, 0);
                acc[i][j] = __builtin_amdgcn_mfma_f32_16x16x32_bf16(
                    fal[i], fbh[j], acc[i][j], 0, 0, 0);
            }
    }

    // epilogue: C/D layout col=lane&15, row=quad*4+reg (m89-verified)
#pragma unroll
    for (int i = 0; i < 4; ++i) {
        const int m = m0 + wm * 64 + i * 16 + q * 4;
#pragma unroll
        for (int j = 0; j < 4; ++j) {
            const int n = n0 + wn * 64 + j * 16 + lm;
            float* cp = C + (size_t)m * Nh + n;
#pragma unroll
            for (int r = 0; r < 4; ++r)
                atomicAdd(cp + (size_t)r * Nh, acc[i][j][r]);
        }
    }
}

// ================= bias + leaky relu, in place =================
__global__ __launch_bounds__(256) void bias_lrelu_kernel(
    float* __restrict__ buf, const float* __restrict__ b, int Nn, int total)
{
    const int idx = blockIdx.x * 256 + threadIdx.x;
    if (idx >= total) return;
    buf[idx] = lrelu(buf[idx] + b[idx % Nn]);
}

// ================= block reduce + atomic helper =================
__device__ __forceinline__ void block_reduce_atomic(float t, float* target)
{
#pragma unroll
    for (int off = 32; off > 0; off >>= 1) t += __shfl_down(t, off, 64);
    __shared__ float lt[4];
    const int wave = threadIdx.x >> 6, lane = threadIdx.x & 63;
    if (lane == 0) lt[wave] = t;
    __syncthreads();
    if (threadIdx.x == 0) atomicAdd(target, lt[0] + lt[1] + lt[2] + lt[3]);
}

// ================= product-of-experts group posterior + kl2 =================
__global__ __launch_bounds__(256) void poe_kernel(
    const float* __restrict__ mu1, const float* __restrict__ lv1,
    float* __restrict__ gmu, float* __restrict__ glv, float* __restrict__ kl)
{
    const int l = blockIdx.x * 256 + threadIdx.x;
    float sp = 0.f, sm = 0.f;
    for (int n = 0; n < N_; ++n) {
        const float lv = lv1[(size_t)n * L_ + l];
        const float p  = expf(-lv);
        sp += p;
        sm += mu1[(size_t)n * L_ + l] * p;
    }
    const float gv = 1.f / sp;
    const float gm = sm * gv;
    const float gl = -logf(sp);
    gmu[l] = gm;
    glv[l] = gl;
    const float t = -0.5f * (1.f + gl) + 0.5f * (gm * gm + gv * gv);
    block_reduce_atomic(t, &kl[1]);
}

// ================= reparameterize + kl1 =================
__global__ __launch_bounds__(256) void reparam_kernel(
    const float* __restrict__ mu0, const float* __restrict__ lv0,
    const float* __restrict__ eps_c, const float* __restrict__ eps_s,
    const float* __restrict__ gmu, const float* __restrict__ glv,
    float* __restrict__ zc, float* __restrict__ zs, float* __restrict__ kl)
{
    const int idx = blockIdx.x * 256 + threadIdx.x;
    const int l = idx & (L_ - 1);
    const float m  = mu0[idx];
    const float lv = lv0[idx];
    zc[idx] = eps_c[idx] * expf(0.5f * lv) + m;
    zs[idx] = eps_s[idx] * expf(0.5f * glv[l]) + gmu[l];
    const float e = expf(lv);
    const float t = -0.5f * (1.f + lv) + 0.5f * (m * m + e * e);
    block_reduce_atomic(t, &kl[0]);
}

// ================= final: BN of decoder outputs + output + loss ============
__global__ __launch_bounds__(256) void final_kernel(
    const float* __restrict__ x, const float* __restrict__ oc,
    const float* __restrict__ os, const float* __restrict__ stC,
    const float* __restrict__ stS, const float* __restrict__ kl,
    float* __restrict__ out)
{
    const int idx = blockIdx.x * 256 + threadIdx.x;
    const float mc = stC[0] * IC_, qc = stC[1] * IC_;
    const float ivc = rsqrtf(qc - mc * mc + 1e-5f);
    const float ms = stS[0] * IC_, qs = stS[1] * IC_;
    const float ivs = rsqrtf(qs - ms * ms + 1e-5f);
    const float tc = lrelu((oc[idx] - mc) * ivc);
    const float ts = fmaxf((os[idx] - ms) * ivs, 0.f);
    const float o = tc * ts;
    const float d = expf(x[idx]) - expf(o);
    out[idx]            = -kl[0] + kl[1] + d * d;
    out[N_ * PIX + idx] = o;
}

// ================= host launch =================
extern "C" void kernel_launch(void* const* d_in, const int* in_sizes, int n_in,
                              void* d_out, int out_size, void* d_ws, size_t ws_size,
                              hipStream_t stream)
{
    const float* x        = (const float*)d_in[0];
    const float* eps_c    = (const float*)d_in[1];
    const float* eps_s    = (const float*)d_in[2];
    const float* enc_cw1  = (const float*)d_in[3];
    const float* enc_cb1  = (const float*)d_in[4];
    const float* enc_cw2  = (const float*)d_in[5];
    const float* enc_cb2  = (const float*)d_in[6];
    const float* enc_cw3  = (const float*)d_in[7];
    const float* enc_cb3  = (const float*)d_in[8];
    const float* enc_muW1 = (const float*)d_in[9];
    const float* enc_muB1 = (const float*)d_in[10];
    const float* enc_muW2 = (const float*)d_in[11];
    const float* enc_muB2 = (const float*)d_in[12];
    const float* enc_vaW1 = (const float*)d_in[13];
    const float* enc_vaB1 = (const float*)d_in[14];
    const float* enc_vaW2 = (const float*)d_in[15];
    const float* enc_vaB2 = (const float*)d_in[16];
    const float* dec_cw1  = (const float*)d_in[17];
    const float* dec_cb1  = (const float*)d_in[18];
    const float* dec_cw2  = (const float*)d_in[19];
    const float* dec_cb2  = (const float*)d_in[20];
    const float* dec_cw3  = (const float*)d_in[21];
    const float* dec_cb3  = (const float*)d_in[22];
    float* out = (float*)d_out;

    // ---- workspace layout (floats) ----
    float* ws   = (float*)d_ws;
    float* bufA = ws;                             // N*64*PIX
    float* bufB = bufA + (size_t)N_ * 64 * PIX;   // N*32*PIX
    float* h1   = bufB + (size_t)N_ * 32 * PIX;   // N*H
    float* h2   = h1 + N_ * H_;
    float* mu0  = h2 + N_ * H_;                   // N*L each below
    float* lv0  = mu0 + N_ * L_;
    float* mu1  = lv0 + N_ * L_;
    float* lv1  = mu1 + N_ * L_;
    float* zc   = lv1 + N_ * L_;
    float* zs   = zc + N_ * L_;
    float* oc   = zs + N_ * L_;
    float* os   = oc + N_ * L_;
    float* gmu  = os + N_ * L_;                   // L
    float* glv  = gmu + L_;                       // L
    float* stats = glv + L_;                      // 12 slots x 128
    float* kl   = stats + 12 * 128;               // 2

    auto st = [&](int s) { return stats + 128 * s; };

    hipMemsetAsync(stats, 0, 12 * 128 * sizeof(float), stream);
    hipMemsetAsync(kl, 0, 2 * sizeof(float), stream);

    // ================== encoders ==================
    for (int i = 0; i < 2; ++i) {
        const float* cw1 = enc_cw1 + (size_t)i * 32 * 9;
        const float* cb1 = enc_cb1 + (size_t)i * 32;
        const float* cw2 = enc_cw2 + (size_t)i * 64 * 32 * 9;
        const float* cb2 = enc_cb2 + (size_t)i * 64;
        const float* cw3 = enc_cw3 + (size_t)i * 32 * 64 * 9;
        const float* cb3 = enc_cb3 + (size_t)i * 32;

        conv3x3<1, 16, false><<<N_ * 2, 256, 0, stream>>>(
            x, cw1, cb1, bufB, nullptr, st(i * 3 + 0), 32);
        conv3x3<32, 16, true><<<N_ * 4, 256, 0, stream>>>(
            bufB, cw2, cb2, bufA, st(i * 3 + 0), st(i * 3 + 1), 64);
        conv3x3<64, 16, true><<<N_ * 2, 256, 0, stream>>>(
            bufA, cw3, cb3, bufB, st(i * 3 + 1), st(i * 3 + 2), 32);
        // bufB = raw conv3 out; BN+lrelu fused into GEMM A staging

        const float* W1m = enc_muW1 + (size_t)i * H_ * F_;
        const float* B1m = enc_muB1 + (size_t)i * H_;
        const float* W2m = enc_muW2 + (size_t)i * L_ * H_;
        const float* B2m = enc_muB2 + (size_t)i * L_;
        const float* W1v = enc_vaW1 + (size_t)i * H_ * F_;
        const float* B1v = enc_vaB1 + (size_t)i * H_;
        const float* W2v = enc_vaW2 + (size_t)i * L_ * H_;
        const float* B2v = enc_vaB2 + (size_t)i * L_;
        float* mu_i = (i == 0) ? mu0 : mu1;
        float* lv_i = (i == 0) ? lv0 : lv1;

        hipMemsetAsync(h1, 0, (size_t)N_ * H_ * sizeof(float), stream);
        hipMemsetAsync(h2, 0, (size_t)N_ * H_ * sizeof(float), stream);
        // W1 (fused mu+va): M=512, N=512, K=32768; split-K 16 -> 512 blocks
        gemm_mfma<true><<<dim3(8, 4, 16), 256, 0, stream>>>(
            bufB, bufB, W1m, W1v, h1, h2, F_, H_, 2048, 4, st(i * 3 + 2), 32);
        bias_lrelu_kernel<<<(N_ * H_) / 256, 256, 0, stream>>>(h1, B1m, H_, N_ * H_);
        bias_lrelu_kernel<<<(N_ * H_) / 256, 256, 0, stream>>>(h2, B1v, H_, N_ * H_);

        hipMemsetAsync(mu_i, 0, (size_t)N_ * L_ * sizeof(float), stream);
        hipMemsetAsync(lv_i, 0, (size_t)N_ * L_ * sizeof(float), stream);
        // W2 (fused mu+va): M=512, N=1024, K=512; split-K 4 -> 256 blocks
        gemm_mfma<false><<<dim3(16, 4, 4), 256, 0, stream>>>(
            h1, h2, W2m, W2v, mu_i, lv_i, H_, L_, 128, 8, nullptr, 0);
        bias_lrelu_kernel<<<(N_ * L_) / 256, 256, 0, stream>>>(mu_i, B2m, L_, N_ * L_);
        bias_lrelu_kernel<<<(N_ * L_) / 256, 256, 0, stream>>>(lv_i, B2v, L_, N_ * L_);
    }

    // ================== PoE + reparam + KL ==================
    poe_kernel<<<L_ / 256, 256, 0, stream>>>(mu1, lv1, gmu, glv, kl);
    reparam_kernel<<<(N_ * L_) / 256, 256, 0, stream>>>(
        mu0, lv0, eps_c, eps_s, gmu, glv, zc, zs, kl);

    // ================== decoders ==================
    for (int i = 0; i < 2; ++i) {
        const float* cw1 = dec_cw1 + (size_t)i * 32 * 9;
        const float* cb1 = dec_cb1 + (size_t)i * 32;
        const float* cw2 = dec_cw2 + (size_t)i * 64 * 32 * 9;
        const float* cb2 = dec_cb2 + (size_t)i * 64;
        const float* cw3 = dec_cw3 + (size_t)i * 64 * 9;
        const float* cb3 = dec_cb3 + (size_t)i * 1;
        const float* zi = (i == 0) ? zc : zs;
        float* oi = (i == 0) ? oc : os;

        conv3x3<1, 16, false><<<N_ * 2, 256, 0, stream>>>(
            zi, cw1, cb1, bufB, nullptr, st(6 + i * 3 + 0), 32);
        conv3x3<32, 16, true><<<N_ * 4, 256, 0, stream>>>(
            bufB, cw2, cb2, bufA, st(6 + i * 3 + 0), st(6 + i * 3 + 1), 64);
        conv3x3<64, 1, true><<<N_, 256, 0, stream>>>(
            bufA, cw3, cb3, oi, st(6 + i * 3 + 1), st(6 + i * 3 + 2), 1);
    }

    // ================== output + loss (BN of oc/os fused) ==================
    final_kernel<<<(N_ * PIX) / 256, 256, 0, stream>>>(
        x, oc, os, st(8), st(11), kl, out);
}

// Round 7
// 1903.016 us; speedup vs baseline: 2.4260x; 1.8791x over previous
//
#include <hip/hip_runtime.h>

// ---------------- problem constants ----------------
constexpr int N_   = 512;
constexpr int PIX  = 1024;    // 32*32
constexpr int L_   = 1024;
constexpr int F_   = 32768;   // 32*32*32
constexpr int H_   = 512;
constexpr float IC_ = 1.0f / (float)(512 * 1024);   // 1/(N*PIX), BN count

__device__ __forceinline__ float lrelu(float t) { return t >= 0.f ? t : 0.01f * t; }

using frag  = __attribute__((ext_vector_type(8))) short;   // 8 bf16 (4 VGPRs)
using f32x4 = __attribute__((ext_vector_type(4))) float;   // MFMA accum

// split v = hi + lo, both bf16 (truncation; lo captures the tail exactly,
// dropped lo*lo term ~2^-16 relative)
__device__ __forceinline__ void split_bf16(float v, short& hi, short& lo) {
    const unsigned b = __float_as_uint(v);
    hi = (short)(b >> 16);
    const float hf = __uint_as_float(b & 0xFFFF0000u);
    lo = (short)(__float_as_uint(v - hf) >> 16);
}

// two ds_read_b64 -> one 8-bf16 fragment (stride-72B LDS rows can't align b128)
__device__ __forceinline__ frag ld2(const short* p) {
    union { frag f; struct { unsigned long long a, b; } u; } x;
    x.u.a = *(const unsigned long long*)(p);
    x.u.b = *(const unsigned long long*)(p + 4);
    return x.f;
}

// ======== weight pre-split: OIHW fp32 -> fragment-ordered bf16 hi/lo ========
// layout: [cc][pos][cot] blocks of 512 shorts, element (lane=q*16+lm, j):
//   value = W[cot*16+lm][cc*32 + q*8 + j][pos]
__global__ __launch_bounds__(256) void wsplit_kernel(
    const float* __restrict__ W, short* __restrict__ hi, short* __restrict__ lo,
    int CIN, int NCOT, int total)
{
    const int idx = blockIdx.x * 256 + threadIdx.x;
    if (idx >= total) return;
    const int j    = idx & 7;
    const int lane = (idx >> 3) & 63;
    const int q    = lane >> 4, lm = lane & 15;
    const int blk  = idx >> 9;
    const int cot  = blk % NCOT;
    const int rest = blk / NCOT;
    const int pos  = rest % 9;
    const int cc   = rest / 9;
    const int co = cot * 16 + lm;
    const int ci = cc * 32 + q * 8 + j;
    short h, l;
    split_bf16(W[((size_t)co * CIN + ci) * 9 + pos], h, l);
    hi[idx] = h; lo[idx] = l;
}

// ======== conv 3x3 SAME via implicit-GEMM MFMA (split-bf16, 3-pass) =========
// Block: one image, 8 output rows (256 px), ALL Cout. 256 thr = 4 waves;
// wave handles px-tiles wv*4..wv*4+3 (16 px each) x all co-tiles.
// LDS: active 32-ci chunk, px-major [340][36] shorts (10 rows x 34 cols halo
// region, zero borders, BN+lrelu applied while staging). B-frag = 2x b64.
// A-frags (weights) from pre-split global (L2-hot broadcast).
// Epilogue: raw conv+bias store + per-channel sum/sumsq into stats_out.
template<int CIN, int COUT, bool BN_IN>
__global__ __launch_bounds__(256) void conv_mfma(
    const float* __restrict__ in, const short* __restrict__ wh,
    const short* __restrict__ wl, const float* __restrict__ bias,
    float* __restrict__ out, const float* __restrict__ stats_in,
    float* __restrict__ stats_out)
{
    constexpr int NCOT = COUT / 16;
    constexpr int NCH  = CIN / 32;
    constexpr int STR  = 36;              // shorts per staged pixel
    constexpr int PLsh = 340 * STR;       // plane: 10 rows x 34 cols
    __shared__ short hiL[PLsh], loL[PLsh];          // ~48 KB
    __shared__ float red[2 * COUT];
    const int tid  = threadIdx.x;
    const int n    = blockIdx.x >> 2;
    const int y0   = (blockIdx.x & 3) << 3;
    const int lane = tid & 63;
    const int wv   = tid >> 6;
    const int lm   = lane & 15;
    const int q    = lane >> 4;

    if (tid < 2 * COUT) red[tid] = 0.f;

    f32x4 acc[NCOT][4];
#pragma unroll
    for (int t = 0; t < NCOT; ++t)
#pragma unroll
        for (int pt = 0; pt < 4; ++pt) acc[t][pt] = {0.f, 0.f, 0.f, 0.f};

    // staging coords: 340 staged px covered by tid and tid+256
    const int rs0 = tid / 34, cs0 = tid % 34;
    const int idx1 = tid + 256;
    const int rs1 = idx1 / 34, cs1 = idx1 % 34;
    const int gr0 = y0 - 1 + rs0, gc0 = cs0 - 1;
    const int gr1 = y0 - 1 + rs1, gc1 = cs1 - 1;
    const bool in1 = idx1 < 340;
    const bool ok0 = ((unsigned)gr0 < 32u) && ((unsigned)gc0 < 32u);
    const bool ok1 = in1 && ((unsigned)gr1 < 32u) && ((unsigned)gc1 < 32u);
    const int  po0 = gr0 * 32 + gc0;
    const int  po1 = gr1 * 32 + gc1;

    const float* inb = in + ((size_t)n * CIN << 10);

#pragma unroll 1
    for (int cc = 0; cc < NCH; ++cc) {
        if (cc) __syncthreads();          // previous chunk's reads done
#pragma unroll 1
        for (int ci = 0; ci < 32; ++ci) {
            const int cg = cc * 32 + ci;
            float m = 0.f, inv = 1.f;
            if (BN_IN) {
                m = stats_in[cg] * IC_;
                const float qq = stats_in[CIN + cg] * IC_;
                inv = rsqrtf(qq - m * m + 1e-5f);
            }
            float v0 = ok0 ? inb[((size_t)cg << 10) + po0] : 0.f;
            if (BN_IN && ok0) v0 = lrelu((v0 - m) * inv);
            short h, l;
            split_bf16(v0, h, l);
            hiL[tid * STR + ci] = h;
            loL[tid * STR + ci] = l;
            if (in1) {
                float v1 = ok1 ? inb[((size_t)cg << 10) + po1] : 0.f;
                if (BN_IN && ok1) v1 = lrelu((v1 - m) * inv);
                short h1, l1;
                split_bf16(v1, h1, l1);
                hiL[idx1 * STR + ci] = h1;
                loL[idx1 * STR + ci] = l1;
            }
        }
        __syncthreads();

#pragma unroll 1
        for (int pos = 0; pos < 9; ++pos) {
            const int ky = pos / 3, kx = pos - ky * 3;
            frag ah[NCOT], al[NCOT];
#pragma unroll
            for (int t = 0; t < NCOT; ++t) {
                const size_t wb =
                    (size_t)(((cc * 9 + pos) * NCOT + t) * 512 + lane * 8);
                ah[t] = *(const frag*)&wh[wb];
                al[t] = *(const frag*)&wl[wb];
            }
#pragma unroll
            for (int pt = 0; pt < 4; ++pt) {
                const int ptile = wv * 4 + pt;
                const int row = ptile >> 1;
                const int col = ((ptile & 1) << 4) + lm;
                const int loff = ((row + ky) * 34 + col + kx) * STR + q * 8;
                const frag bh = ld2(&hiL[loff]);
                const frag bl = ld2(&loL[loff]);
#pragma unroll
                for (int t = 0; t < NCOT; ++t) {
                    acc[t][pt] = __builtin_amdgcn_mfma_f32_16x16x32_bf16(
                        ah[t], bh, acc[t][pt], 0, 0, 0);
                    acc[t][pt] = __builtin_amdgcn_mfma_f32_16x16x32_bf16(
                        ah[t], bl, acc[t][pt], 0, 0, 0);
                    acc[t][pt] = __builtin_amdgcn_mfma_f32_16x16x32_bf16(
                        al[t], bh, acc[t][pt], 0, 0, 0);
                }
            }
        }
    }

    // ---- epilogue: bias, store raw, per-channel stats ----
    // C/D: col(n=px)=lane&15, row(m=co within tile)=q*4+reg
    float* ob = out + ((size_t)n * COUT << 10);
#pragma unroll
    for (int t = 0; t < NCOT; ++t) {
#pragma unroll
        for (int r = 0; r < 4; ++r) {
            const int co = t * 16 + q * 4 + r;
            const float b = bias[co];
            float s = 0.f, sq = 0.f;
#pragma unroll
            for (int pt = 0; pt < 4; ++pt) {
                const float v = acc[t][pt][r] + b;
                ob[((size_t)co << 10) + (y0 << 5) + ((wv * 4 + pt) << 4) + lm] = v;
                s += v; sq += v * v;
            }
#pragma unroll
            for (int off = 8; off > 0; off >>= 1) {
                s  += __shfl_down(s, off, 64);
                sq += __shfl_down(sq, off, 64);
            }
            if (lm == 0) {
                atomicAdd(&red[co], s);
                atomicAdd(&red[COUT + co], sq);
            }
        }
    }
    __syncthreads();
    if (tid < 2 * COUT) atomicAdd(&stats_out[tid], red[tid]);
}

// ================= conv 3x3 VALU (round-4 proven) — conv1 & dec-conv3 only ===
template<int CIN, int COPB, bool BN_IN>
__global__ __launch_bounds__(256) void conv3x3(
    const float* __restrict__ in, const float* __restrict__ w,
    const float* __restrict__ bias, float* __restrict__ out,
    const float* __restrict__ stats_in, float* __restrict__ stats_out,
    int Cout)
{
    constexpr int CT = (CIN < 4) ? CIN : 4;
    __shared__ float tile[CT * PIX];
    __shared__ float red[2 * COPB];
    const int groups = Cout / COPB;
    const int n   = blockIdx.x / groups;
    const int co0 = (blockIdx.x % groups) * COPB;
    const int tid = threadIdx.x;
    const int x   = tid & 31;
    const int y0  = (tid >> 5) * 4;

    float acc[COPB][4];
#pragma unroll
    for (int c = 0; c < COPB; ++c)
#pragma unroll
        for (int j = 0; j < 4; ++j) acc[c][j] = 0.f;

    const float* inbase = in + (size_t)n * CIN * PIX;

#pragma unroll 1
    for (int s0 = 0; s0 < CIN; s0 += CT) {
        __syncthreads();
#pragma unroll
        for (int s = 0; s < CT; ++s) {
            float4 v = ((const float4*)(inbase + (size_t)(s0 + s) * PIX))[tid];
            if (BN_IN) {
                const int c = s0 + s;
                const float m   = stats_in[c] * IC_;
                const float q   = stats_in[CIN + c] * IC_;
                const float inv = rsqrtf(q - m * m + 1e-5f);
                v.x = lrelu((v.x - m) * inv);
                v.y = lrelu((v.y - m) * inv);
                v.z = lrelu((v.z - m) * inv);
                v.w = lrelu((v.w - m) * inv);
            }
            ((float4*)tile)[s * 256 + tid] = v;
        }
        __syncthreads();
#pragma unroll 2
        for (int s = 0; s < CT; ++s) {
            const int ci = s0 + s;
            const float* tp = tile + s * PIX;
            float r[6][3];
#pragma unroll
            for (int ry = 0; ry < 6; ++ry) {
                const int yy = y0 + ry - 1;
                const bool yok = (unsigned)yy < 32u;
#pragma unroll
                for (int cx = 0; cx < 3; ++cx) {
                    const int xx = x + cx - 1;
                    const bool ok = yok && ((unsigned)xx < 32u);
                    r[ry][cx] = ok ? tp[yy * 32 + xx] : 0.f;
                }
            }
#pragma unroll
            for (int c = 0; c < COPB; ++c) {
                const float* wp = w + ((size_t)(co0 + c) * CIN + ci) * 9;
#pragma unroll
                for (int ky = 0; ky < 3; ++ky)
#pragma unroll
                    for (int kx = 0; kx < 3; ++kx) {
                        const float wv = wp[ky * 3 + kx];
#pragma unroll
                        for (int j = 0; j < 4; ++j)
                            acc[c][j] += r[ky + j][kx] * wv;
                    }
            }
        }
    }

    if (tid < 2 * COPB) red[tid] = 0.f;
    __syncthreads();
#pragma unroll
    for (int c = 0; c < COPB; ++c) {
        const float b = bias[co0 + c];
        float* ob = out + (((size_t)n * Cout + co0 + c) << 10);
        float s = 0.f, q = 0.f;
#pragma unroll
        for (int j = 0; j < 4; ++j) {
            const float v = acc[c][j] + b;
            ob[(y0 + j) * 32 + x] = v;
            s += v; q += v * v;
        }
#pragma unroll
        for (int off = 32; off > 0; off >>= 1) {
            s += __shfl_down(s, off, 64);
            q += __shfl_down(q, off, 64);
        }
        if ((tid & 63) == 0) {
            atomicAdd(&red[c], s);
            atomicAdd(&red[COPB + c], q);
        }
    }
    __syncthreads();
    if (tid < COPB)
        atomicAdd(&stats_out[co0 + tid], red[tid]);
    else if (tid < 2 * COPB)
        atomicAdd(&stats_out[Cout + co0 + tid - COPB], red[tid]);
}

// ======== split-bf16 MFMA GEMM (round-6 proven): C += A(MxK) * B(NxK)^T =====
template<bool BN_A>
__global__ __launch_bounds__(256) void gemm_mfma(
    const float* __restrict__ A0, const float* __restrict__ A1,
    const float* __restrict__ B0, const float* __restrict__ B1,
    float* __restrict__ C0, float* __restrict__ C1,
    int K, int Nh, int kchunk, int xph,
    const float* __restrict__ bnstats, int Cin)
{
    __shared__ short AhL[4096], AlL[4096], BhL[4096], BlL[4096];  // 32 KB
    const int tid  = threadIdx.x;
    const int head = blockIdx.x / xph;
    const int n0   = (blockIdx.x % xph) * 128;
    const int m0   = blockIdx.y * 128;
    const float* A = head ? A1 : A0;
    const float* B = head ? B1 : B0;
    float*       C = head ? C1 : C0;
    const int k0 = blockIdx.z * kchunk;
    const int k1 = k0 + kchunk;

    const int lane = tid & 63;
    const int wv   = tid >> 6;
    const int wm   = wv & 1;
    const int wn   = wv >> 1;
    const int lm   = lane & 15;
    const int q    = lane >> 4;

    const int srow = tid >> 1;
    const int smt  = srow >> 4;
    const int slm  = srow & 15;
    const int sq0  = (tid & 1) * 2;
    const int ks   = (tid & 1) * 16;

    f32x4 acc[4][4];
#pragma unroll
    for (int i = 0; i < 4; ++i)
#pragma unroll
        for (int j = 0; j < 4; ++j) acc[i][j] = {0.f, 0.f, 0.f, 0.f};

    auto cv8 = [](float4 u, float4 w2, frag& h, frag& l) {
        const float v[8] = {u.x, u.y, u.z, u.w, w2.x, w2.y, w2.z, w2.w};
#pragma unroll
        for (int e = 0; e < 8; ++e) {
            short hh, ll;
            split_bf16(v[e], hh, ll);
            h[e] = hh; l[e] = ll;
        }
    };

#pragma unroll 1
    for (int kb = k0; kb < k1; kb += 32) {
        const float* Ap = A + (size_t)(m0 + srow) * K + kb + ks;
        const float* Bp = B + (size_t)(n0 + srow) * K + kb + ks;
        float4 a4[4], b4[4];
#pragma unroll
        for (int g = 0; g < 4; ++g) a4[g] = ((const float4*)Ap)[g];
#pragma unroll
        for (int g = 0; g < 4; ++g) b4[g] = ((const float4*)Bp)[g];

        if (BN_A) {
            const int c = (kb + ks) >> 10;
            const float m   = bnstats[c] * IC_;
            const float qq  = bnstats[Cin + c] * IC_;
            const float inv = rsqrtf(qq - m * m + 1e-5f);
#pragma unroll
            for (int g = 0; g < 4; ++g) {
                a4[g].x = lrelu((a4[g].x - m) * inv);
                a4[g].y = lrelu((a4[g].y - m) * inv);
                a4[g].z = lrelu((a4[g].z - m) * inv);
                a4[g].w = lrelu((a4[g].w - m) * inv);
            }
        }

        frag ah0, al0, ah1, al1, bh0, bl0, bh1, bl1;
        cv8(a4[0], a4[1], ah0, al0);
        cv8(a4[2], a4[3], ah1, al1);
        cv8(b4[0], b4[1], bh0, bl0);
        cv8(b4[2], b4[3], bh1, bl1);

        __syncthreads();
        const int o0 = ((smt * 4 + sq0) * 16 + slm) * 8;
        const int o1 = ((smt * 4 + sq0 + 1) * 16 + slm) * 8;
        *(frag*)&AhL[o0] = ah0;  *(frag*)&AhL[o1] = ah1;
        *(frag*)&AlL[o0] = al0;  *(frag*)&AlL[o1] = al1;
        *(frag*)&BhL[o0] = bh0;  *(frag*)&BhL[o1] = bh1;
        *(frag*)&BlL[o0] = bl0;  *(frag*)&BlL[o1] = bl1;
        __syncthreads();

        frag fah[4], fal[4], fbh[4], fbl[4];
#pragma unroll
        for (int t = 0; t < 4; ++t) {
            const int oa = (((wm * 4 + t) * 4 + q) * 16 + lm) * 8;
            const int ob = (((wn * 4 + t) * 4 + q) * 16 + lm) * 8;
            fah[t] = *(const frag*)&AhL[oa];
            fal[t] = *(const frag*)&AlL[oa];
            fbh[t] = *(const frag*)&BhL[ob];
            fbl[t] = *(const frag*)&BlL[ob];
        }
#pragma unroll
        for (int i = 0; i < 4; ++i)
#pragma unroll
            for (int j = 0; j < 4; ++j) {
                acc[i][j] = __builtin_amdgcn_mfma_f32_16x16x32_bf16(
                    fah[i], fbh[j], acc[i][j], 0, 0, 0);
                acc[i][j] = __builtin_amdgcn_mfma_f32_16x16x32_bf16(
                    fah[i], fbl[j], acc[i][j], 0, 0, 0);
                acc[i][j] = __builtin_amdgcn_mfma_f32_16x16x32_bf16(
                    fal[i], fbh[j], acc[i][j], 0, 0, 0);
            }
    }

#pragma unroll
    for (int i = 0; i < 4; ++i) {
        const int m = m0 + wm * 64 + i * 16 + q * 4;
#pragma unroll
        for (int j = 0; j < 4; ++j) {
            const int n = n0 + wn * 64 + j * 16 + lm;
            float* cp = C + (size_t)m * Nh + n;
#pragma unroll
            for (int r = 0; r < 4; ++r)
                atomicAdd(cp + (size_t)r * Nh, acc[i][j][r]);
        }
    }
}

// ================= bias + leaky relu, in place =================
__global__ __launch_bounds__(256) void bias_lrelu_kernel(
    float* __restrict__ buf, const float* __restrict__ b, int Nn, int total)
{
    const int idx = blockIdx.x * 256 + threadIdx.x;
    if (idx >= total) return;
    buf[idx] = lrelu(buf[idx] + b[idx % Nn]);
}

// ================= block reduce + atomic helper =================
__device__ __forceinline__ void block_reduce_atomic(float t, float* target)
{
#pragma unroll
    for (int off = 32; off > 0; off >>= 1) t += __shfl_down(t, off, 64);
    __shared__ float lt[4];
    const int wave = threadIdx.x >> 6, lane = threadIdx.x & 63;
    if (lane == 0) lt[wave] = t;
    __syncthreads();
    if (threadIdx.x == 0) atomicAdd(target, lt[0] + lt[1] + lt[2] + lt[3]);
}

// ================= product-of-experts group posterior + kl2 =================
__global__ __launch_bounds__(256) void poe_kernel(
    const float* __restrict__ mu1, const float* __restrict__ lv1,
    float* __restrict__ gmu, float* __restrict__ glv, float* __restrict__ kl)
{
    const int l = blockIdx.x * 256 + threadIdx.x;
    float sp = 0.f, sm = 0.f;
    for (int n = 0; n < N_; ++n) {
        const float lv = lv1[(size_t)n * L_ + l];
        const float p  = expf(-lv);
        sp += p;
        sm += mu1[(size_t)n * L_ + l] * p;
    }
    const float gv = 1.f / sp;
    const float gm = sm * gv;
    const float gl = -logf(sp);
    gmu[l] = gm;
    glv[l] = gl;
    const float t = -0.5f * (1.f + gl) + 0.5f * (gm * gm + gv * gv);
    block_reduce_atomic(t, &kl[1]);
}

// ================= reparameterize + kl1 =================
__global__ __launch_bounds__(256) void reparam_kernel(
    const float* __restrict__ mu0, const float* __restrict__ lv0,
    const float* __restrict__ eps_c, const float* __restrict__ eps_s,
    const float* __restrict__ gmu, const float* __restrict__ glv,
    float* __restrict__ zc, float* __restrict__ zs, float* __restrict__ kl)
{
    const int idx = blockIdx.x * 256 + threadIdx.x;
    const int l = idx & (L_ - 1);
    const float m  = mu0[idx];
    const float lv = lv0[idx];
    zc[idx] = eps_c[idx] * expf(0.5f * lv) + m;
    zs[idx] = eps_s[idx] * expf(0.5f * glv[l]) + gmu[l];
    const float e = expf(lv);
    const float t = -0.5f * (1.f + lv) + 0.5f * (m * m + e * e);
    block_reduce_atomic(t, &kl[0]);
}

// ================= final: BN of decoder outputs + output + loss ============
__global__ __launch_bounds__(256) void final_kernel(
    const float* __restrict__ x, const float* __restrict__ oc,
    const float* __restrict__ os, const float* __restrict__ stC,
    const float* __restrict__ stS, const float* __restrict__ kl,
    float* __restrict__ out)
{
    const int idx = blockIdx.x * 256 + threadIdx.x;
    const float mc = stC[0] * IC_, qc = stC[1] * IC_;
    const float ivc = rsqrtf(qc - mc * mc + 1e-5f);
    const float ms = stS[0] * IC_, qs = stS[1] * IC_;
    const float ivs = rsqrtf(qs - ms * ms + 1e-5f);
    const float tc = lrelu((oc[idx] - mc) * ivc);
    const float ts = fmaxf((os[idx] - ms) * ivs, 0.f);
    const float o = tc * ts;
    const float d = expf(x[idx]) - expf(o);
    out[idx]            = -kl[0] + kl[1] + d * d;
    out[N_ * PIX + idx] = o;
}

// ================= host launch =================
extern "C" void kernel_launch(void* const* d_in, const int* in_sizes, int n_in,
                              void* d_out, int out_size, void* d_ws, size_t ws_size,
                              hipStream_t stream)
{
    const float* x        = (const float*)d_in[0];
    const float* eps_c    = (const float*)d_in[1];
    const float* eps_s    = (const float*)d_in[2];
    const float* enc_cw1  = (const float*)d_in[3];
    const float* enc_cb1  = (const float*)d_in[4];
    const float* enc_cw2  = (const float*)d_in[5];
    const float* enc_cb2  = (const float*)d_in[6];
    const float* enc_cw3  = (const float*)d_in[7];
    const float* enc_cb3  = (const float*)d_in[8];
    const float* enc_muW1 = (const float*)d_in[9];
    const float* enc_muB1 = (const float*)d_in[10];
    const float* enc_muW2 = (const float*)d_in[11];
    const float* enc_muB2 = (const float*)d_in[12];
    const float* enc_vaW1 = (const float*)d_in[13];
    const float* enc_vaB1 = (const float*)d_in[14];
    const float* enc_vaW2 = (const float*)d_in[15];
    const float* enc_vaB2 = (const float*)d_in[16];
    const float* dec_cw1  = (const float*)d_in[17];
    const float* dec_cb1  = (const float*)d_in[18];
    const float* dec_cw2  = (const float*)d_in[19];
    const float* dec_cb2  = (const float*)d_in[20];
    const float* dec_cw3  = (const float*)d_in[21];
    const float* dec_cb3  = (const float*)d_in[22];
    float* out = (float*)d_out;

    // ---- workspace layout (floats) ----
    float* ws   = (float*)d_ws;
    float* bufA = ws;                             // N*64*PIX
    float* bufB = bufA + (size_t)N_ * 64 * PIX;   // N*32*PIX
    float* h1   = bufB + (size_t)N_ * 32 * PIX;   // N*H
    float* h2   = h1 + N_ * H_;
    float* mu0  = h2 + N_ * H_;                   // N*L each below
    float* lv0  = mu0 + N_ * L_;
    float* mu1  = lv0 + N_ * L_;
    float* lv1  = mu1 + N_ * L_;
    float* zc   = lv1 + N_ * L_;
    float* zs   = zc + N_ * L_;
    float* oc   = zs + N_ * L_;
    float* os   = oc + N_ * L_;
    float* gmu  = os + N_ * L_;                   // L
    float* glv  = gmu + L_;                       // L
    float* stats = glv + L_;                      // 12 slots x 128
    float* kl   = stats + 12 * 128;               // 4 (2 used, pad to align)
    // pre-split conv weights (16-B aligned: float offset is multiple of 4)
    short* wsh  = (short*)(kl + 4);               // 6 layers x 18432 shorts (hi)
    short* wsl  = wsh + 6 * 18432;                // (lo)

    auto st  = [&](int s) { return stats + 128 * s; };
    auto whp = [&](int layer) { return wsh + layer * 18432; };
    auto wlp = [&](int layer) { return wsl + layer * 18432; };

    hipMemsetAsync(stats, 0, 12 * 128 * sizeof(float), stream);
    hipMemsetAsync(kl, 0, 2 * sizeof(float), stream);

    // pre-split conv weights into MFMA fragment order (all 6 big-conv layers)
    // layers: 0=enc0.cw2  1=enc0.cw3  2=enc1.cw2  3=enc1.cw3  4=dec0.cw2  5=dec1.cw2
    wsplit_kernel<<<72, 256, 0, stream>>>(enc_cw2,            whp(0), wlp(0), 32, 4, 18432);
    wsplit_kernel<<<72, 256, 0, stream>>>(enc_cw3,            whp(1), wlp(1), 64, 2, 18432);
    wsplit_kernel<<<72, 256, 0, stream>>>(enc_cw2 + 64*32*9,  whp(2), wlp(2), 32, 4, 18432);
    wsplit_kernel<<<72, 256, 0, stream>>>(enc_cw3 + 32*64*9,  whp(3), wlp(3), 64, 2, 18432);
    wsplit_kernel<<<72, 256, 0, stream>>>(dec_cw2,            whp(4), wlp(4), 32, 4, 18432);
    wsplit_kernel<<<72, 256, 0, stream>>>(dec_cw2 + 64*32*9,  whp(5), wlp(5), 32, 4, 18432);

    // ================== encoders ==================
    for (int i = 0; i < 2; ++i) {
        const float* cw1 = enc_cw1 + (size_t)i * 32 * 9;
        const float* cb1 = enc_cb1 + (size_t)i * 32;
        const float* cb2 = enc_cb2 + (size_t)i * 64;
        const float* cb3 = enc_cb3 + (size_t)i * 32;

        conv3x3<1, 16, false><<<N_ * 2, 256, 0, stream>>>(
            x, cw1, cb1, bufB, nullptr, st(i * 3 + 0), 32);
        conv_mfma<32, 64, true><<<N_ * 4, 256, 0, stream>>>(
            bufB, whp(i * 2), wlp(i * 2), cb2, bufA, st(i * 3 + 0), st(i * 3 + 1));
        conv_mfma<64, 32, true><<<N_ * 4, 256, 0, stream>>>(
            bufA, whp(i * 2 + 1), wlp(i * 2 + 1), cb3, bufB, st(i * 3 + 1), st(i * 3 + 2));
        // bufB = raw conv3 out; BN+lrelu fused into GEMM A staging

        const float* W1m = enc_muW1 + (size_t)i * H_ * F_;
        const float* B1m = enc_muB1 + (size_t)i * H_;
        const float* W2m = enc_muW2 + (size_t)i * L_ * H_;
        const float* B2m = enc_muB2 + (size_t)i * L_;
        const float* W1v = enc_vaW1 + (size_t)i * H_ * F_;
        const float* B1v = enc_vaB1 + (size_t)i * H_;
        const float* W2v = enc_vaW2 + (size_t)i * L_ * H_;
        const float* B2v = enc_vaB2 + (size_t)i * L_;
        float* mu_i = (i == 0) ? mu0 : mu1;
        float* lv_i = (i == 0) ? lv0 : lv1;

        hipMemsetAsync(h1, 0, (size_t)N_ * H_ * sizeof(float), stream);
        hipMemsetAsync(h2, 0, (size_t)N_ * H_ * sizeof(float), stream);
        gemm_mfma<true><<<dim3(8, 4, 16), 256, 0, stream>>>(
            bufB, bufB, W1m, W1v, h1, h2, F_, H_, 2048, 4, st(i * 3 + 2), 32);
        bias_lrelu_kernel<<<(N_ * H_) / 256, 256, 0, stream>>>(h1, B1m, H_, N_ * H_);
        bias_lrelu_kernel<<<(N_ * H_) / 256, 256, 0, stream>>>(h2, B1v, H_, N_ * H_);

        hipMemsetAsync(mu_i, 0, (size_t)N_ * L_ * sizeof(float), stream);
        hipMemsetAsync(lv_i, 0, (size_t)N_ * L_ * sizeof(float), stream);
        gemm_mfma<false><<<dim3(16, 4, 4), 256, 0, stream>>>(
            h1, h2, W2m, W2v, mu_i, lv_i, H_, L_, 128, 8, nullptr, 0);
        bias_lrelu_kernel<<<(N_ * L_) / 256, 256, 0, stream>>>(mu_i, B2m, L_, N_ * L_);
        bias_lrelu_kernel<<<(N_ * L_) / 256, 256, 0, stream>>>(lv_i, B2v, L_, N_ * L_);
    }

    // ================== PoE + reparam + KL ==================
    poe_kernel<<<L_ / 256, 256, 0, stream>>>(mu1, lv1, gmu, glv, kl);
    reparam_kernel<<<(N_ * L_) / 256, 256, 0, stream>>>(
        mu0, lv0, eps_c, eps_s, gmu, glv, zc, zs, kl);

    // ================== decoders ==================
    for (int i = 0; i < 2; ++i) {
        const float* cw1 = dec_cw1 + (size_t)i * 32 * 9;
        const float* cb1 = dec_cb1 + (size_t)i * 32;
        const float* cb2 = dec_cb2 + (size_t)i * 64;
        const float* cw3 = dec_cw3 + (size_t)i * 64 * 9;
        const float* cb3 = dec_cb3 + (size_t)i * 1;
        const float* zi = (i == 0) ? zc : zs;
        float* oi = (i == 0) ? oc : os;

        conv3x3<1, 16, false><<<N_ * 2, 256, 0, stream>>>(
            zi, cw1, cb1, bufB, nullptr, st(6 + i * 3 + 0), 32);
        conv_mfma<32, 64, true><<<N_ * 4, 256, 0, stream>>>(
            bufB, whp(4 + i), wlp(4 + i), cb2, bufA, st(6 + i * 3 + 0), st(6 + i * 3 + 1));
        conv3x3<64, 1, true><<<N_, 256, 0, stream>>>(
            bufA, cw3, cb3, oi, st(6 + i * 3 + 1), st(6 + i * 3 + 2), 1);
    }

    // ================== output + loss (BN of oc/os fused) ==================
    final_kernel<<<(N_ * PIX) / 256, 256, 0, stream>>>(
        x, oc, os, st(8), st(11), kl, out);
}